// Round 1
// baseline (243.477 us; speedup 1.0000x reference)
//
#include <hip/hip_runtime.h>

// TokenEmbedding segment-sum, MI355X. Two-phase gather, wave-streaming v2.
//
//  Phase 1: build lower-bound table start[b][t] (t in 0..L) via boundary
//           scatter (tok is sorted per batch). Stride padded to L+8 so the
//           5-boundary loads in phase 2 can vectorize (L+1=4097 broke 16B
//           alignment for odd b).
//
//  Phase 2 (rewritten): one WAVE per 4 consecutive tokens instead of one
//           256-thread block per token. Since tok is sorted, the runs of 4
//           consecutive tokens are ADJACENT in w -> each wave streams a
//           contiguous range of input rows. Per row: 4 independent float4
//           loads per lane (64 lanes x 4 float4 = 1024 floats = full row),
//           giving 4-8 loads in flight per wave vs 1 before. Boundary loads
//           amortized 4x. 2048 blocks x 256 thr = 32 waves/CU (full occ).
//
// Each input row read once, each output row written once. Empty runs store
// zeros (handles poisoned d_out without a memset pass).

#define B_DIM 8
#define L_DIM 4096
#define H_DIM 1024
#define LSTRIDE (L_DIM + 8)   // start-table row stride (ints); 4104*4 B, 16B-aligned
#define TPW 4                 // tokens per wave

__global__ __launch_bounds__(256) void build_starts_kernel(
    const int* __restrict__ tok,   // [B, L] sorted per batch
    int* __restrict__ start)       // [B, LSTRIDE], entries 0..L valid
{
    const int gid = blockIdx.x * 256 + threadIdx.x;   // 0 .. B*L-1
    const int b = gid >> 12;
    const int w = gid & (L_DIM - 1);

    const int* __restrict__ row = tok + (size_t)b * L_DIM;
    const int cur  = row[w];
    const int prev = (w > 0) ? row[w - 1] : -1;

    int* __restrict__ srow = start + (size_t)b * LSTRIDE;
    for (int t = prev + 1; t <= cur; ++t) srow[t] = w;
    if (w == L_DIM - 1) {
        for (int t = cur + 1; t <= L_DIM; ++t) srow[t] = L_DIM;
    }
}

__device__ __forceinline__ void acc4(float4& a, const float4 v) {
    a.x += v.x; a.y += v.y; a.z += v.z; a.w += v.w;
}

__global__ __launch_bounds__(256) void token_seg_sum_kernel(
    const float* __restrict__ seq,   // [B, L, H] fp32
    const int* __restrict__ start,   // [B, LSTRIDE]
    float* __restrict__ out)         // [B, L, H] fp32
{
    const int wid   = (blockIdx.x << 2) | (threadIdx.x >> 6);  // global wave id
    const int lane  = threadIdx.x & 63;
    const int tglob = wid * TPW;                 // flat (b,t) of first token
    const int b     = tglob >> 12;
    const int t0    = tglob & (L_DIM - 1);

    // Preload the TPW+1 run boundaries (wave-uniform broadcast loads).
    const int* __restrict__ srow = start + b * LSTRIDE + t0;
    int st[TPW + 1];
#pragma unroll
    for (int i = 0; i <= TPW; ++i) st[i] = srow[i];

    // b * L * H / 4 float4 = b << 20 ; row w is 256 float4.
    const float4* __restrict__ base  = (const float4*)seq + ((size_t)b << 20);
    float4* __restrict__       obase = (float4*)out + ((size_t)tglob << 8);

#pragma unroll
    for (int i = 0; i < TPW; ++i) {
        float4 a0 = make_float4(0.f, 0.f, 0.f, 0.f);
        float4 a1 = a0, a2 = a0, a3 = a0;

        const int s = st[i];
        const int e = st[i + 1];
        for (int w = s; w < e; ++w) {
            const float4* __restrict__ r = base + ((size_t)w << 8) + lane;
            // 4 independent 16B loads per lane; lanes consecutive -> 1KB/instr
            float4 v0 = r[0];
            float4 v1 = r[64];
            float4 v2 = r[128];
            float4 v3 = r[192];
            acc4(a0, v0); acc4(a1, v1); acc4(a2, v2); acc4(a3, v3);
        }

        float4* __restrict__ o = obase + (i << 8) + lane;
        o[0]   = a0;
        o[64]  = a1;
        o[128] = a2;
        o[192] = a3;
    }
}

extern "C" void kernel_launch(void* const* d_in, const int* in_sizes, int n_in,
                              void* d_out, int out_size, void* d_ws, size_t ws_size,
                              hipStream_t stream) {
    const float* seq = (const float*)d_in[0];
    const int*   tok = (const int*)d_in[1];
    float*       out = (float*)d_out;
    int*         start = (int*)d_ws;            // B*LSTRIDE ints = 131.3 KB

    build_starts_kernel<<<dim3(B_DIM * L_DIM / 256), dim3(256), 0, stream>>>(tok, start);

    // B*L tokens / TPW per wave / 4 waves per block = 2048 blocks
    token_seg_sum_kernel<<<dim3(B_DIM * L_DIM / (TPW * 4)), dim3(256), 0, stream>>>(
        seq, start, out);
}

// Round 3
// 238.568 us; speedup vs baseline: 1.0206x; 1.0206x over previous
//
#include <hip/hip_runtime.h>

// TokenEmbedding segment-sum, MI355X. Two-phase gather, v3b.
//
//  Phase 1: build lower-bound table start[b][t] (t in 0..L) via boundary
//           scatter (tok is sorted per batch). Row stride padded to L+8.
//
//  Phase 2 (v3 changes vs v2):
//   - TPW=2 tokens/wave (4096 blocks): finer grains -> two scheduling
//     generations per CU, smaller straggler tail (was 48% time-avg occ).
//   - 2-row unrolled inner loop: 8 independent float4 loads (8 KB/wave)
//     in flight before the vmcnt wait, vs 4 KB in v2.
//   - NONTEMPORAL output stores (via native ext_vector_type(4) float —
//     HIP's float4 class is rejected by the builtin): output is never
//     re-read; nt stores skip L2/L3 allocation so the 134 MB/iter write
//     stream stops evicting the input, which then stays L3-resident
//     across iterations (FETCH_SIZE was 67 MB = half the input re-fetched
//     from HBM each iter).
//
// Each input row read once, each output row written once. Empty runs store
// zeros (handles poisoned d_out without a memset pass).

#define B_DIM 8
#define L_DIM 4096
#define H_DIM 1024
#define LSTRIDE (L_DIM + 8)   // start-table row stride (ints)
#define TPW 2                 // tokens per wave

typedef float fx4 __attribute__((ext_vector_type(4)));   // native vec for nt store

__global__ __launch_bounds__(256) void build_starts_kernel(
    const int* __restrict__ tok,   // [B, L] sorted per batch
    int* __restrict__ start)       // [B, LSTRIDE], entries 0..L valid
{
    const int gid = blockIdx.x * 256 + threadIdx.x;   // 0 .. B*L-1
    const int b = gid >> 12;
    const int w = gid & (L_DIM - 1);

    const int* __restrict__ row = tok + (size_t)b * L_DIM;
    const int cur  = row[w];
    const int prev = (w > 0) ? row[w - 1] : -1;

    int* __restrict__ srow = start + (size_t)b * LSTRIDE;
    for (int t = prev + 1; t <= cur; ++t) srow[t] = w;
    if (w == L_DIM - 1) {
        for (int t = cur + 1; t <= L_DIM; ++t) srow[t] = L_DIM;
    }
}

__device__ __forceinline__ void acc4(fx4& a, const float4 v) {
    a.x += v.x; a.y += v.y; a.z += v.z; a.w += v.w;
}

__global__ __launch_bounds__(256) void token_seg_sum_kernel(
    const float* __restrict__ seq,   // [B, L, H] fp32
    const int* __restrict__ start,   // [B, LSTRIDE]
    float* __restrict__ out)         // [B, L, H] fp32
{
    const int wid   = (blockIdx.x << 2) | (threadIdx.x >> 6);  // global wave id
    const int lane  = threadIdx.x & 63;
    const int tglob = wid * TPW;                 // flat (b,t) of first token
    const int b     = tglob >> 12;
    const int t0    = tglob & (L_DIM - 1);

    // Preload the TPW+1 run boundaries (wave-uniform broadcast loads).
    const int* __restrict__ srow = start + b * LSTRIDE + t0;
    int st[TPW + 1];
#pragma unroll
    for (int i = 0; i <= TPW; ++i) st[i] = srow[i];

    // b * L * H / 4 float4 = b << 20 ; each row is 256 float4.
    const float4* __restrict__ base  = (const float4*)seq + ((size_t)b << 20);
    fx4* __restrict__          obase = (fx4*)out + ((size_t)tglob << 8);

#pragma unroll
    for (int i = 0; i < TPW; ++i) {
        fx4 a0 = (fx4)0.f;
        fx4 a1 = a0, a2 = a0, a3 = a0;

        const int s = st[i];
        const int e = st[i + 1];
        int w = s;
        // 2-row unroll: 8 independent 1KB-per-instr loads in flight.
        for (; w + 2 <= e; w += 2) {
            const float4* __restrict__ r0 = base + ((size_t)w << 8) + lane;
            const float4* __restrict__ r1 = r0 + 256;
            float4 v0 = r0[0];
            float4 v1 = r0[64];
            float4 v2 = r0[128];
            float4 v3 = r0[192];
            float4 u0 = r1[0];
            float4 u1 = r1[64];
            float4 u2 = r1[128];
            float4 u3 = r1[192];
            acc4(a0, v0); acc4(a1, v1); acc4(a2, v2); acc4(a3, v3);
            acc4(a0, u0); acc4(a1, u1); acc4(a2, u2); acc4(a3, u3);
        }
        if (w < e) {
            const float4* __restrict__ r0 = base + ((size_t)w << 8) + lane;
            float4 v0 = r0[0];
            float4 v1 = r0[64];
            float4 v2 = r0[128];
            float4 v3 = r0[192];
            acc4(a0, v0); acc4(a1, v1); acc4(a2, v2); acc4(a3, v3);
        }

        // Nontemporal stores: never re-read; keep L2/L3 for the input.
        fx4* __restrict__ o = obase + (i << 8) + lane;
        __builtin_nontemporal_store(a0, o);
        __builtin_nontemporal_store(a1, o + 64);
        __builtin_nontemporal_store(a2, o + 128);
        __builtin_nontemporal_store(a3, o + 192);
    }
}

extern "C" void kernel_launch(void* const* d_in, const int* in_sizes, int n_in,
                              void* d_out, int out_size, void* d_ws, size_t ws_size,
                              hipStream_t stream) {
    const float* seq = (const float*)d_in[0];
    const int*   tok = (const int*)d_in[1];
    float*       out = (float*)d_out;
    int*         start = (int*)d_ws;            // B*LSTRIDE ints = 131.3 KB

    build_starts_kernel<<<dim3(B_DIM * L_DIM / 256), dim3(256), 0, stream>>>(tok, start);

    // B*L tokens / TPW per wave / 4 waves per block = 4096 blocks
    token_seg_sum_kernel<<<dim3(B_DIM * L_DIM / (TPW * 4)), dim3(256), 0, stream>>>(
        seq, start, out);
}

// Round 4
// 230.298 us; speedup vs baseline: 1.0572x; 1.0359x over previous
//
#include <hip/hip_runtime.h>

// TokenEmbedding segment-sum, MI355X. Two-phase gather, v4.
//
// v2/v3 (wave-per-token) POST-MORTEM: regression vs the round-0 structure
// (~80 us vs ~68 us). nt stores did not change FETCH_SIZE (the harness's
// 512 MiB poison fill flushes L3 each iter; write-allocate was not the
// evictor). Reverting to the empirically-fastest geometry: one 256-thread
// block per token (32768 blocks). Its advantages over wave-per-token:
//   - boundary loads are provably wave-uniform (t from blockIdx) -> the
//     compiler emits s_load on the scalar path, off the vector-MSHR path;
//   - 131072 short waves = maximal TLP, fine-grained scheduling, no tail;
//   - each thread owns one float4 column slot -> trivially coalesced 1KB
//     per wave-load.
// Polish added on top of round-0:
//   - 2-row unrolled run loop, two independent accumulators (2 loads in
//     flight when a token has >=2 wordpieces);
//   - nontemporal output stores (output never re-read; keep L2 read-side);
//   - native ext_vector float4 ops throughout.
//
//  Phase 1: build lower-bound table start[b][t] (t in 0..L) via boundary
//           scatter (tok sorted per batch). Row stride padded to L+8.
//  Phase 2: block bt=(b,t): rows [start[t], start[t+1]) summed, one
//           coalesced row store. Empty runs store zeros (handles poisoned
//           d_out without a memset pass).

#define B_DIM 8
#define L_DIM 4096
#define H_DIM 1024
#define LSTRIDE (L_DIM + 8)   // start-table row stride (ints)

typedef float fx4 __attribute__((ext_vector_type(4)));

__global__ __launch_bounds__(256) void build_starts_kernel(
    const int* __restrict__ tok,   // [B, L] sorted per batch
    int* __restrict__ start)       // [B, LSTRIDE], entries 0..L valid
{
    const int gid = blockIdx.x * 256 + threadIdx.x;   // 0 .. B*L-1
    const int b = gid >> 12;
    const int w = gid & (L_DIM - 1);

    const int* __restrict__ row = tok + (size_t)b * L_DIM;
    const int cur  = row[w];
    const int prev = (w > 0) ? row[w - 1] : -1;

    int* __restrict__ srow = start + (size_t)b * LSTRIDE;
    for (int t = prev + 1; t <= cur; ++t) srow[t] = w;
    if (w == L_DIM - 1) {
        for (int t = cur + 1; t <= L_DIM; ++t) srow[t] = L_DIM;
    }
}

__global__ __launch_bounds__(256) void token_seg_sum_kernel(
    const float* __restrict__ seq,   // [B, L, H] fp32
    const int* __restrict__ start,   // [B, LSTRIDE]
    float* __restrict__ out)         // [B, L, H] fp32
{
    const int bt = blockIdx.x;            // 0 .. B*L-1  (flat token id)
    const int b  = bt >> 12;
    const int t  = bt & (L_DIM - 1);

    // Wave-uniform (blockIdx-derived) -> scalar-path s_load, off the
    // vector memory queue.
    const int* __restrict__ srow = start + b * LSTRIDE;
    const int s = srow[t];
    const int e = srow[t + 1];

    const int tid = threadIdx.x;          // one float4 column slot each
    const fx4* __restrict__ base = (const fx4*)seq + ((size_t)b << 20);

    fx4 acc0 = (fx4)0.f;
    fx4 acc1 = (fx4)0.f;
    int w = s;
    for (; w + 2 <= e; w += 2) {          // 2 independent loads in flight
        fx4 v0 = base[((size_t)w << 8) + tid];
        fx4 v1 = base[((size_t)(w + 1) << 8) + tid];
        acc0 += v0;
        acc1 += v1;
    }
    if (w < e) {
        acc0 += base[((size_t)w << 8) + tid];
    }
    acc0 += acc1;

    // Output never re-read: nontemporal store keeps L2/L3 for the input.
    fx4* __restrict__ o = (fx4*)out + ((size_t)bt << 8) + tid;
    __builtin_nontemporal_store(acc0, o);
}

extern "C" void kernel_launch(void* const* d_in, const int* in_sizes, int n_in,
                              void* d_out, int out_size, void* d_ws, size_t ws_size,
                              hipStream_t stream) {
    const float* seq = (const float*)d_in[0];
    const int*   tok = (const int*)d_in[1];
    float*       out = (float*)d_out;
    int*         start = (int*)d_ws;            // B*LSTRIDE ints = 131.3 KB

    build_starts_kernel<<<dim3(B_DIM * L_DIM / 256), dim3(256), 0, stream>>>(tok, start);
    token_seg_sum_kernel<<<dim3(B_DIM * L_DIM), dim3(256), 0, stream>>>(seq, start, out);
}